// Round 1
// 106.614 us; speedup vs baseline: 1.0234x; 1.0234x over previous
//
#include <hip/hip_runtime.h>
#include <hip/hip_bf16.h>

#define TOTALW 10000
#define BATCH 8192
#define SEQ   80
#define EMBD  100
#define UNITS 64
#define MB    16
#define NTHREADS 256
#define HPAD  80    // H row stride in halfs: 160 B -> frag-read start banks 2-way (free)
#define TOKPAD 84   // int stride: li*84 mod 32 -> 2-way max (free); [80..83] zeroed tail

typedef __attribute__((ext_vector_type(8))) _Float16 half8;
typedef __attribute__((ext_vector_type(2))) _Float16 half2v;
typedef __attribute__((ext_vector_type(4))) float floatx4;

// pack two fp32 -> fp16x2 dword (RTZ; |err| ~2.4e-4, fine for h in (-1,1))
__device__ __forceinline__ half2v pkh(float a, float b) {
#if __has_builtin(__builtin_amdgcn_cvt_pkrtz)
  return (half2v)__builtin_amdgcn_cvt_pkrtz(a, b);
#else
  return half2v{(_Float16)a, (_Float16)b};
#endif
}
__device__ __forceinline__ int h2i(half2v h) {
  union { half2v h; int i; } c; c.h = h; return c.i;
}
// packed tanh: deg-7 odd poly (economized-Chebyshev on [-0.75,0.75]),
// evaluated in v_pk_fma_f16: 5 packed ops for 2 values (vs 10 scalar fp32).
// fp16 eval err ~1e-3 worst case; h storage quantum 8x finer than bf16.
__device__ __forceinline__ half2v pk_tanh(half2v x) {
  const half2v c3 = {(_Float16)-0.0359280f, (_Float16)-0.0359280f};
  const half2v c2 = {(_Float16) 0.1270784f, (_Float16) 0.1270784f};
  const half2v c1 = {(_Float16)-0.3324617f, (_Float16)-0.3324617f};
  const half2v c0 = {(_Float16) 0.9999660f, (_Float16) 0.9999660f};
  const half2v t = x * x;
  half2v p = __builtin_elementwise_fma(c3, t, c2);
  p = __builtin_elementwise_fma(p, t, c1);
  p = __builtin_elementwise_fma(p, t, c0);
  return x * p;
}

// ---- kernel 1: xw = emb @ W1x + b1 via MFMA (fp16 in, fp32 out) ----
// 512 blocks, 2-tile loop: evens the 625-tile tail (vs 625 blocks = 2.44 rounds/CU)
__launch_bounds__(256)
__global__ void emb_proj_mfma(const float* __restrict__ emb,
                              const float* __restrict__ W1x,
                              const float* __restrict__ b1,
                              float* __restrict__ xw) {
  __shared__ __align__(16) _Float16 Es[16][128];
  const int tid  = threadIdx.x;
  const int wave = tid >> 6;
  const int lane = tid & 63;
  const int li   = lane & 15;
  const int quad = lane >> 4;
  const int q4   = quad * 4;

  // W1x fragments + bias: tile-independent, hoisted out of the tile loop
  half8 bw[4];
  #pragma unroll
  for (int kc = 0; kc < 4; ++kc) {
    half8 f;
    #pragma unroll
    for (int j = 0; j < 8; ++j) {
      const int k = kc * 32 + quad * 8 + j;
      f[j] = (k < EMBD) ? (_Float16)W1x[k * UNITS + wave * 16 + li] : (_Float16)0.0f;
    }
    bw[kc] = f;
  }
  const float bb = b1[wave * 16 + li];

  // zero-pad cols [100,128) once (never overwritten by staging)
  for (int task = tid; task < 16 * 14; task += 256) {
    const int r = task / 14, c = task % 14;
    *(int*)(&Es[r][100 + c * 2]) = 0;
  }

  for (int rowBase = blockIdx.x * 16; rowBase < TOTALW; rowBase += 512 * 16) {
    __syncthreads();   // Es safe to overwrite (previous tile's readers done)
    for (int task = tid; task < 16 * 25; task += 256) {
      const int r = task / 25, c = task % 25;
      const float4 v = *(const float4*)(emb + (rowBase + r) * EMBD + c * 4);
      *(int2*)(&Es[r][c * 4]) = make_int2(h2i(pkh(v.x, v.y)), h2i(pkh(v.z, v.w)));
    }
    __syncthreads();
    floatx4 acc = {bb, bb, bb, bb};
    #pragma unroll
    for (int kc = 0; kc < 4; ++kc) {
      const half8 a = *(const half8*)(&Es[li][kc * 32 + quad * 8]);
      acc = __builtin_amdgcn_mfma_f32_16x16x32_f16(a, bw[kc], acc, 0, 0, 0);
    }
    #pragma unroll
    for (int i = 0; i < 4; ++i)
      xw[(rowBase + q4 + i) * UNITS + wave * 16 + li] = acc[i];
  }
}

// ---- kernel 2: recurrence, operand-swapped MFMA (A=W^T, B=h^T), fp16 h ----
//  A-frag (weights): lane(li,q) j -> W[32kc+8q+j][16w+li]
//  B-frag (h): lane(li,q) j -> h[row li][32kc+8q+j]  = ds_read_b128
//  D: lane(li,q) reg r -> h_out[row li][16w+4q+r]    = packed ds_write_b64
__launch_bounds__(NTHREADS, 2)
__global__ void rnn2_kernel(const int* __restrict__ tokens,
                            const float* __restrict__ xw,
                            const float* __restrict__ W1h,
                            const float* __restrict__ W2x,
                            const float* __restrict__ W2h,
                            const float* __restrict__ b2,
                            const float* __restrict__ Wd,
                            const float* __restrict__ bd,
                            float* __restrict__ out)
{
  __shared__ __align__(16) _Float16 H1s[2][MB][HPAD];
  __shared__ __align__(16) _Float16 H2s[2][MB][HPAD];
  __shared__ __align__(16) int      tok[MB][TOKPAD];

  const int tid  = threadIdx.x;
  const int wave = tid >> 6;
  const int lane = tid & 63;
  const int li   = lane & 15;
  const int quad = lane >> 4;
  const int u     = wave * 16 + li;
  const int ubase = wave * 16 + quad * 4;
  const int rowBase = blockIdx.x * MB;

  for (int task = tid; task < MB * 20; task += NTHREADS) {
    const int r = task / 20, c = task % 20;
    *(int4*)(&tok[r][c * 4]) = *(const int4*)(tokens + (rowBase + r) * SEQ + c * 4);
  }
  for (int task = tid; task < MB * 4; task += NTHREADS)
    tok[task >> 2][SEQ + (task & 3)] = 0;   // tail: unconditional t+4 reads land here
  for (int i = tid; i < MB * HPAD / 2; i += NTHREADS)
    ((int*)&H2s[1][0][0])[i] = 0;   // h2_{-1} = 0

  half8 w1h[2], w2x[2], w2h[2];
  #pragma unroll
  for (int kc = 0; kc < 2; ++kc) {
    half8 f, g, h;
    #pragma unroll
    for (int j = 0; j < 8; ++j) {
      const int k = kc * 32 + quad * 8 + j;
      f[j] = (_Float16)W1h[k * UNITS + u];
      g[j] = (_Float16)W2x[k * UNITS + u];
      h[j] = (_Float16)W2h[k * UNITS + u];
    }
    w1h[kc] = f; w2x[kc] = g; w2h[kc] = h;
  }
  const float4 b2f = *(const float4*)(b2 + ubase);

  // head weights hoisted (wave 0 only uses them; off the step critical path)
  float4 wdv[4];
  float  bdv = 0.f;
  if (wave == 0) {
    const int s = lane & 3;
    #pragma unroll
    for (int i = 0; i < 4; ++i)
      wdv[i] = *(const float4*)(Wd + s * 16 + i * 4);
    bdv = bd[0];
  }

  __syncthreads();   // tokens + zeroed H2 visible

  // ---- prologue: h1_0 = tanh(xw[tok_0]); xw0 = xw_1; tok queue depth 2 ----
  float4 xw0, xw1;
  {
    const int tk0 = tok[li][0];
    const float4 x0 = *(const float4*)(xw + tk0 * UNITS + ubase);
    *(int2*)(&H1s[0][li][ubase]) = make_int2(h2i(pk_tanh(pkh(x0.x, x0.y))),
                                             h2i(pk_tanh(pkh(x0.z, x0.w))));
    const int tk1 = tok[li][1];
    xw0 = *(const float4*)(xw + tk1 * UNITS + ubase);
  }
  int tkA = tok[li][2];   // token for step-(T)'s xw_{T+2} load, T even
  int tkB = tok[li][3];   // T odd
  __syncthreads();        // h1_0 visible

  // step T: computes h2_T and h1_{T+1}; TKU holds tok[li][T+2] (read 2 steps ago)
  // acc2 split into two chains (accA: W2x+bias, accB: W2h) -> dep depth 2, not 4
  // XWC/XWN: register-rotated xw prefetch (no per-step float4 copy)
#define STEP(T, CUR, NXT, TKU, PF, XWC, XWN)                                    \
  {                                                                             \
    if (PF) {                                                                   \
      XWN = *(const float4*)(xw + (TKU) * UNITS + ubase);                       \
      TKU = tok[li][(T) + 4];                                                   \
    }                                                                           \
    const half8 h1a0 = *(const half8*)(&H1s[CUR][li][quad * 8]);                \
    const half8 h1a1 = *(const half8*)(&H1s[CUR][li][32 + quad * 8]);           \
    const half8 h2a0 = *(const half8*)(&H2s[NXT][li][quad * 8]);                \
    const half8 h2a1 = *(const half8*)(&H2s[NXT][li][32 + quad * 8]);           \
    floatx4 accA = {b2f.x, b2f.y, b2f.z, b2f.w};                                \
    floatx4 accB = {0.f, 0.f, 0.f, 0.f};                                        \
    accA = __builtin_amdgcn_mfma_f32_16x16x32_f16(w2x[0], h1a0, accA, 0, 0, 0); \
    accB = __builtin_amdgcn_mfma_f32_16x16x32_f16(w2h[0], h2a0, accB, 0, 0, 0); \
    accA = __builtin_amdgcn_mfma_f32_16x16x32_f16(w2x[1], h1a1, accA, 0, 0, 0); \
    accB = __builtin_amdgcn_mfma_f32_16x16x32_f16(w2h[1], h2a1, accB, 0, 0, 0); \
    floatx4 acc1 = {(XWC).x, (XWC).y, (XWC).z, (XWC).w};                        \
    acc1 = __builtin_amdgcn_mfma_f32_16x16x32_f16(w1h[0], h1a0, acc1, 0, 0, 0); \
    acc1 = __builtin_amdgcn_mfma_f32_16x16x32_f16(w1h[1], h1a1, acc1, 0, 0, 0); \
    const half2v s0 = pk_tanh(pkh(accA[0] + accB[0], accA[1] + accB[1]));       \
    const half2v s1 = pk_tanh(pkh(accA[2] + accB[2], accA[3] + accB[3]));       \
    *(int2*)(&H2s[CUR][li][ubase]) = make_int2(h2i(s0), h2i(s1));               \
    const half2v c0 = pk_tanh(pkh(acc1[0], acc1[1]));                           \
    const half2v c1 = pk_tanh(pkh(acc1[2], acc1[3]));                           \
    *(int2*)(&H1s[NXT][li][ubase]) = make_int2(h2i(c0), h2i(c1));               \
    __syncthreads();                                                            \
  }

  for (int t = 0; t < SEQ - 2; t += 2) {   // t = 0..76: steps 0..77
    STEP(t,     0, 1, tkA, 1, xw0, xw1)
    STEP(t + 1, 1, 0, tkB, 1, xw1, xw0)
  }
  STEP(SEQ - 2, 0, 1, tkA, 0, xw0, xw1)   // step 78: h2_78, h1_79

  // ---- h2_79 ----
  {
    const half8 h1a0 = *(const half8*)(&H1s[1][li][quad * 8]);
    const half8 h1a1 = *(const half8*)(&H1s[1][li][32 + quad * 8]);
    const half8 h2a0 = *(const half8*)(&H2s[0][li][quad * 8]);
    const half8 h2a1 = *(const half8*)(&H2s[0][li][32 + quad * 8]);
    floatx4 accA = {b2f.x, b2f.y, b2f.z, b2f.w};
    floatx4 accB = {0.f, 0.f, 0.f, 0.f};
    accA = __builtin_amdgcn_mfma_f32_16x16x32_f16(w2x[0], h1a0, accA, 0, 0, 0);
    accB = __builtin_amdgcn_mfma_f32_16x16x32_f16(w2h[0], h2a0, accB, 0, 0, 0);
    accA = __builtin_amdgcn_mfma_f32_16x16x32_f16(w2x[1], h1a1, accA, 0, 0, 0);
    accB = __builtin_amdgcn_mfma_f32_16x16x32_f16(w2h[1], h2a1, accB, 0, 0, 0);
    const half2v s0 = pk_tanh(pkh(accA[0] + accB[0], accA[1] + accB[1]));
    const half2v s1 = pk_tanh(pkh(accA[2] + accB[2], accA[3] + accB[3]));
    *(int2*)(&H2s[1][li][ubase]) = make_int2(h2i(s0), h2i(s1));
  }
  __syncthreads();

  // ---- head: wave-parallel dot (4 lanes per row, 16 FMA each + 2 shfl) ----
  if (wave == 0) {
    const int r = lane >> 2, s = lane & 3;
    const _Float16* hrow = &H2s[1][r][0];
    float acc = 0.f;
    #pragma unroll
    for (int i = 0; i < 4; ++i) {
      const int base = s * 16 + i * 4;
      acc += (float)hrow[base + 0] * wdv[i].x + (float)hrow[base + 1] * wdv[i].y
           + (float)hrow[base + 2] * wdv[i].z + (float)hrow[base + 3] * wdv[i].w;
    }
    acc += __shfl_xor(acc, 1);
    acc += __shfl_xor(acc, 2);
    if (s == 0) out[rowBase + r] = 1.0f / (1.0f + __expf(-(acc + bdv)));
  }
#undef STEP
}

extern "C" void kernel_launch(void* const* d_in, const int* in_sizes, int n_in,
                              void* d_out, int out_size, void* d_ws, size_t ws_size,
                              hipStream_t stream) {
  const int*   tokens = (const int*)d_in[0];
  const float* emb    = (const float*)d_in[1];
  const float* W1x    = (const float*)d_in[2];
  const float* W1h    = (const float*)d_in[3];
  const float* b1     = (const float*)d_in[4];
  const float* W2x    = (const float*)d_in[5];
  const float* W2h    = (const float*)d_in[6];
  const float* b2     = (const float*)d_in[7];
  const float* Wd     = (const float*)d_in[8];
  const float* bd     = (const float*)d_in[9];
  float* out = (float*)d_out;
  float* xw  = (float*)d_ws;   // 10000*64*4 = 2.56 MB

  emb_proj_mfma<<<512, 256, 0, stream>>>(emb, W1x, b1, xw);
  rnn2_kernel<<<BATCH / MB, NTHREADS, 0, stream>>>(tokens, xw, W1h, W2x, W2h,
                                                   b2, Wd, bd, out);
}

// Round 2
// 103.716 us; speedup vs baseline: 1.0520x; 1.0279x over previous
//
#include <hip/hip_runtime.h>
#include <hip/hip_bf16.h>

#define TOTALW 10000
#define BATCH 8192
#define SEQ   80
#define EMBD  100
#define UNITS 64
#define MB    16
#define NTHREADS 256
#define HPAD  80    // H row stride in halfs: 160 B -> frag-read start banks 2-way (free)
#define TOKPAD 84   // int stride: li*84 mod 32 -> 2-way max (free); [80..83] zeroed tail

typedef __attribute__((ext_vector_type(8))) _Float16 half8;
typedef __attribute__((ext_vector_type(2))) _Float16 half2v;
typedef __attribute__((ext_vector_type(4))) float floatx4;

// pack two fp32 -> fp16x2 dword (RTZ; |err| ~2.4e-4, fine for h in (-1,1))
__device__ __forceinline__ half2v pkh(float a, float b) {
#if __has_builtin(__builtin_amdgcn_cvt_pkrtz)
  return (half2v)__builtin_amdgcn_cvt_pkrtz(a, b);
#else
  return half2v{(_Float16)a, (_Float16)b};
#endif
}
__device__ __forceinline__ int h2i(half2v h) {
  union { half2v h; int i; } c; c.h = h; return c.i;
}
__device__ __forceinline__ half2v i2h(int i) {
  union { int i; half2v h; } c; c.i = i; return c.h;
}
// packed tanh: deg-7 odd poly (economized-Chebyshev on [-0.75,0.75]),
// evaluated in v_pk_fma_f16: 5 packed ops for 2 values.
__device__ __forceinline__ half2v pk_tanh(half2v x) {
  const half2v c3 = {(_Float16)-0.0359280f, (_Float16)-0.0359280f};
  const half2v c2 = {(_Float16) 0.1270784f, (_Float16) 0.1270784f};
  const half2v c1 = {(_Float16)-0.3324617f, (_Float16)-0.3324617f};
  const half2v c0 = {(_Float16) 0.9999660f, (_Float16) 0.9999660f};
  const half2v t = x * x;
  half2v p = __builtin_elementwise_fma(c3, t, c2);
  p = __builtin_elementwise_fma(p, t, c1);
  p = __builtin_elementwise_fma(p, t, c0);
  return x * p;
}

// ---- kernel 1: xw = fp16(emb @ W1x + b1), operand-swapped MFMA ----
//  A-frag (weights): lane(li,q) j -> W1x[32kc+8q+j][16w+li]
//  B-frag (emb): lane(li,q) j -> Es[row li][32kc+8q+j]  = ds_read_b128
//  D: lane(li,q) reg r -> xw[rowBase+li][16w+4q+r]      = packed int2 store
// 625 blocks, all co-resident (4KB LDS), one round.
__launch_bounds__(256)
__global__ void emb_proj_mfma(const float* __restrict__ emb,
                              const float* __restrict__ W1x,
                              const float* __restrict__ b1,
                              _Float16* __restrict__ xw) {
  __shared__ __align__(16) _Float16 Es[16][128];
  const int tid  = threadIdx.x;
  const int wave = tid >> 6;
  const int lane = tid & 63;
  const int li   = lane & 15;
  const int quad = lane >> 4;
  const int rowBase = blockIdx.x * 16;          // 625 * 16 = 10000

  for (int task = tid; task < 16 * 25; task += 256) {
    const int r = task / 25, c = task % 25;
    const float4 v = *(const float4*)(emb + (rowBase + r) * EMBD + c * 4);
    *(int2*)(&Es[r][c * 4]) = make_int2(h2i(pkh(v.x, v.y)), h2i(pkh(v.z, v.w)));
  }
  for (int task = tid; task < 16 * 14; task += 256) {
    const int r = task / 14, c = task % 14;
    *(int*)(&Es[r][100 + c * 2]) = 0;
  }
  half8 aw[4];
  #pragma unroll
  for (int kc = 0; kc < 4; ++kc) {
    half8 f;
    #pragma unroll
    for (int j = 0; j < 8; ++j) {
      const int k = kc * 32 + quad * 8 + j;
      f[j] = (k < EMBD) ? (_Float16)W1x[k * UNITS + wave * 16 + li] : (_Float16)0.0f;
    }
    aw[kc] = f;
  }
  const float4 b1v = *(const float4*)(b1 + wave * 16 + quad * 4);
  __syncthreads();

  floatx4 acc = {b1v.x, b1v.y, b1v.z, b1v.w};
  #pragma unroll
  for (int kc = 0; kc < 4; ++kc) {
    const half8 b = *(const half8*)(&Es[li][kc * 32 + quad * 8]);
    acc = __builtin_amdgcn_mfma_f32_16x16x32_f16(aw[kc], b, acc, 0, 0, 0);
  }
  const half2v p0 = pkh(acc[0], acc[1]);
  const half2v p1 = pkh(acc[2], acc[3]);
  *(int2*)(xw + (rowBase + li) * UNITS + wave * 16 + quad * 4) =
      make_int2(h2i(p0), h2i(p1));
}

// ---- kernel 2: recurrence, operand-swapped MFMA (A=W^T, B=h^T), fp16 h ----
//  A-frag (weights): lane(li,q) j -> W[32kc+8q+j][16w+li]
//  B-frag (h): lane(li,q) j -> h[row li][32kc+8q+j]  = ds_read_b128
//  D: lane(li,q) reg r -> h_out[row li][16w+4q+r]    = packed ds_write_b64
__launch_bounds__(NTHREADS, 2)
__global__ void rnn2_kernel(const int* __restrict__ tokens,
                            const _Float16* __restrict__ xw,
                            const float* __restrict__ W1h,
                            const float* __restrict__ W2x,
                            const float* __restrict__ W2h,
                            const float* __restrict__ b2,
                            const float* __restrict__ Wd,
                            const float* __restrict__ bd,
                            float* __restrict__ out)
{
  __shared__ __align__(16) _Float16 H1s[2][MB][HPAD];
  __shared__ __align__(16) _Float16 H2s[2][MB][HPAD];
  __shared__ __align__(16) int      tok[MB][TOKPAD];

  const int tid  = threadIdx.x;
  const int wave = tid >> 6;
  const int lane = tid & 63;
  const int li   = lane & 15;
  const int quad = lane >> 4;
  const int u     = wave * 16 + li;
  const int ubase = wave * 16 + quad * 4;
  const int rowBase = blockIdx.x * MB;

  for (int task = tid; task < MB * 20; task += NTHREADS) {
    const int r = task / 20, c = task % 20;
    *(int4*)(&tok[r][c * 4]) = *(const int4*)(tokens + (rowBase + r) * SEQ + c * 4);
  }
  for (int task = tid; task < MB * 4; task += NTHREADS)
    tok[task >> 2][SEQ + (task & 3)] = 0;   // tail: unconditional t+4 reads land here
  for (int i = tid; i < MB * HPAD / 2; i += NTHREADS)
    ((int*)&H2s[1][0][0])[i] = 0;   // h2_{-1} = 0

  half8 w1h[2], w2x[2], w2h[2];
  #pragma unroll
  for (int kc = 0; kc < 2; ++kc) {
    half8 f, g, h;
    #pragma unroll
    for (int j = 0; j < 8; ++j) {
      const int k = kc * 32 + quad * 8 + j;
      f[j] = (_Float16)W1h[k * UNITS + u];
      g[j] = (_Float16)W2x[k * UNITS + u];
      h[j] = (_Float16)W2h[k * UNITS + u];
    }
    w1h[kc] = f; w2x[kc] = g; w2h[kc] = h;
  }
  const float4 b2f = *(const float4*)(b2 + ubase);

  // head weights hoisted (wave 0 only; off the step critical path)
  float4 wdv[4];
  float  bdv = 0.f;
  if (wave == 0) {
    const int s = lane & 3;
    #pragma unroll
    for (int i = 0; i < 4; ++i)
      wdv[i] = *(const float4*)(Wd + s * 16 + i * 4);
    bdv = bd[0];
  }

  __syncthreads();   // tokens + zeroed H2 visible

  // ---- prologue: h1_0 = tanh(xw[tok_0]); xw0 = xw_1; tok queue depth 2 ----
  int2 xw0, xw1;
  {
    const int tk0 = tok[li][0];
    const int2 x0 = *(const int2*)(xw + tk0 * UNITS + ubase);
    *(int2*)(&H1s[0][li][ubase]) = make_int2(h2i(pk_tanh(i2h(x0.x))),
                                             h2i(pk_tanh(i2h(x0.y))));
    const int tk1 = tok[li][1];
    xw0 = *(const int2*)(xw + tk1 * UNITS + ubase);
  }
  int tkA = tok[li][2];   // token for step-(T)'s xw_{T+2} load, T even
  int tkB = tok[li][3];   // T odd
  __syncthreads();        // h1_0 visible

  // step T: computes h2_T and h1_{T+1}; TKU holds tok[li][T+2] (read 2 steps ago)
  // acc2 split into two chains (accA: W2x+bias, accB: W2h) -> dep depth 2
  // acc1: loop-invariant zero C-quad; xw added post-MFMA via v_pk_add_f16
  // XWC/XWN: register-rotated int2 xw prefetch
#define STEP(T, CUR, NXT, TKU, PF, XWC, XWN)                                    \
  {                                                                             \
    if (PF) {                                                                   \
      XWN = *(const int2*)(xw + (TKU) * UNITS + ubase);                         \
      TKU = tok[li][(T) + 4];                                                   \
    }                                                                           \
    const half8 h1a0 = *(const half8*)(&H1s[CUR][li][quad * 8]);                \
    const half8 h1a1 = *(const half8*)(&H1s[CUR][li][32 + quad * 8]);           \
    const half8 h2a0 = *(const half8*)(&H2s[NXT][li][quad * 8]);                \
    const half8 h2a1 = *(const half8*)(&H2s[NXT][li][32 + quad * 8]);           \
    floatx4 accA = {b2f.x, b2f.y, b2f.z, b2f.w};                                \
    floatx4 accB = {0.f, 0.f, 0.f, 0.f};                                        \
    floatx4 acc1 = {0.f, 0.f, 0.f, 0.f};                                        \
    accA = __builtin_amdgcn_mfma_f32_16x16x32_f16(w2x[0], h1a0, accA, 0, 0, 0); \
    accB = __builtin_amdgcn_mfma_f32_16x16x32_f16(w2h[0], h2a0, accB, 0, 0, 0); \
    accA = __builtin_amdgcn_mfma_f32_16x16x32_f16(w2x[1], h1a1, accA, 0, 0, 0); \
    accB = __builtin_amdgcn_mfma_f32_16x16x32_f16(w2h[1], h2a1, accB, 0, 0, 0); \
    acc1 = __builtin_amdgcn_mfma_f32_16x16x32_f16(w1h[0], h1a0, acc1, 0, 0, 0); \
    acc1 = __builtin_amdgcn_mfma_f32_16x16x32_f16(w1h[1], h1a1, acc1, 0, 0, 0); \
    const half2v s0 = pk_tanh(pkh(accA[0] + accB[0], accA[1] + accB[1]));       \
    const half2v s1 = pk_tanh(pkh(accA[2] + accB[2], accA[3] + accB[3]));       \
    *(int2*)(&H2s[CUR][li][ubase]) = make_int2(h2i(s0), h2i(s1));               \
    const half2v c0 = pk_tanh(i2h((XWC).x) + pkh(acc1[0], acc1[1]));            \
    const half2v c1 = pk_tanh(i2h((XWC).y) + pkh(acc1[2], acc1[3]));            \
    *(int2*)(&H1s[NXT][li][ubase]) = make_int2(h2i(c0), h2i(c1));               \
    __syncthreads();                                                            \
  }

  for (int t = 0; t < SEQ - 2; t += 2) {   // t = 0..76: steps 0..77
    STEP(t,     0, 1, tkA, 1, xw0, xw1)
    STEP(t + 1, 1, 0, tkB, 1, xw1, xw0)
  }
  STEP(SEQ - 2, 0, 1, tkA, 0, xw0, xw1)   // step 78: h2_78, h1_79

  // ---- h2_79 ----
  {
    const half8 h1a0 = *(const half8*)(&H1s[1][li][quad * 8]);
    const half8 h1a1 = *(const half8*)(&H1s[1][li][32 + quad * 8]);
    const half8 h2a0 = *(const half8*)(&H2s[0][li][quad * 8]);
    const half8 h2a1 = *(const half8*)(&H2s[0][li][32 + quad * 8]);
    floatx4 accA = {b2f.x, b2f.y, b2f.z, b2f.w};
    floatx4 accB = {0.f, 0.f, 0.f, 0.f};
    accA = __builtin_amdgcn_mfma_f32_16x16x32_f16(w2x[0], h1a0, accA, 0, 0, 0);
    accB = __builtin_amdgcn_mfma_f32_16x16x32_f16(w2h[0], h2a0, accB, 0, 0, 0);
    accA = __builtin_amdgcn_mfma_f32_16x16x32_f16(w2x[1], h1a1, accA, 0, 0, 0);
    accB = __builtin_amdgcn_mfma_f32_16x16x32_f16(w2h[1], h2a1, accB, 0, 0, 0);
    const half2v s0 = pk_tanh(pkh(accA[0] + accB[0], accA[1] + accB[1]));
    const half2v s1 = pk_tanh(pkh(accA[2] + accB[2], accA[3] + accB[3]));
    *(int2*)(&H2s[1][li][ubase]) = make_int2(h2i(s0), h2i(s1));
  }
  __syncthreads();

  // ---- head: wave-parallel dot (4 lanes per row, 16 FMA each + 2 shfl) ----
  if (wave == 0) {
    const int r = lane >> 2, s = lane & 3;
    const _Float16* hrow = &H2s[1][r][0];
    float acc = 0.f;
    #pragma unroll
    for (int i = 0; i < 4; ++i) {
      const int base = s * 16 + i * 4;
      acc += (float)hrow[base + 0] * wdv[i].x + (float)hrow[base + 1] * wdv[i].y
           + (float)hrow[base + 2] * wdv[i].z + (float)hrow[base + 3] * wdv[i].w;
    }
    acc += __shfl_xor(acc, 1);
    acc += __shfl_xor(acc, 2);
    if (s == 0) out[rowBase + r] = 1.0f / (1.0f + __expf(-(acc + bdv)));
  }
#undef STEP
}

extern "C" void kernel_launch(void* const* d_in, const int* in_sizes, int n_in,
                              void* d_out, int out_size, void* d_ws, size_t ws_size,
                              hipStream_t stream) {
  const int*   tokens = (const int*)d_in[0];
  const float* emb    = (const float*)d_in[1];
  const float* W1x    = (const float*)d_in[2];
  const float* W1h    = (const float*)d_in[3];
  const float* b1     = (const float*)d_in[4];
  const float* W2x    = (const float*)d_in[5];
  const float* W2h    = (const float*)d_in[6];
  const float* b2     = (const float*)d_in[7];
  const float* Wd     = (const float*)d_in[8];
  const float* bd     = (const float*)d_in[9];
  float* out = (float*)d_out;
  _Float16* xw = (_Float16*)d_ws;   // 10000*64*2 = 1.28 MB (fits L2 per XCD)

  emb_proj_mfma<<<TOTALW / 16, 256, 0, stream>>>(emb, W1x, b1, xw);
  rnn2_kernel<<<BATCH / MB, NTHREADS, 0, stream>>>(tokens, xw, W1h, W2x, W2h,
                                                   b2, Wd, bd, out);
}